// Round 1
// baseline (51775.989 us; speedup 1.0000x reference)
//
#include <hip/hip_runtime.h>

// LSTM(H=1024) over SEQ=8192, input_size=1, fused persistent kernel.
// 128 workgroups x 512 threads. Wave w of wg g owns h-index j = 8g+w and its
// 4 gate rows (j, j+1024, j+2048, j+3072) of W_hh, held in 64 VGPRs/thread.
// Cross-wg recurrence via step-numbered per-wg flags + double-buffered h in ws,
// agent-scope (L2-bypass) stores + acquire fence before reads.

#define SEQ 8192
#define HID 1024
#define NWG 128
#define TPB 512
#define WPW 8   // waves (h-indices) per workgroup

__device__ __forceinline__ float fast_sigmoid(float z) {
    float e = __builtin_amdgcn_exp2f(-1.4426950408889634f * z);
    return 1.0f / (1.0f + e);
}
__device__ __forceinline__ float fast_tanh(float x) {
    // tanh(x) = 1 - 2/(exp2(2*log2(e)*x)+1); saturates correctly at +/-inf
    float e = __builtin_amdgcn_exp2f(2.8853900817779268f * x);
    return 1.0f - 2.0f / (e + 1.0f);
}

// ws/out are re-poisoned 0xAA before every launch: zero flags + h buffers,
// prefill out[t] = b_lin (partials are fully overwritten each step).
__global__ void init_kernel(unsigned* flags, float* h_buf, float* out,
                            const float* __restrict__ b_lin) {
    int i = blockIdx.x * blockDim.x + threadIdx.x;
    if (i < NWG) flags[i] = 0u;
    if (i < 2 * HID) h_buf[i] = 0.0f;
    if (i < SEQ) out[i] = b_lin[0];
}

__global__ void finish_kernel(const float* __restrict__ partials,
                              float* __restrict__ out) {
    int t = blockIdx.x * blockDim.x + threadIdx.x;
    if (t >= SEQ) return;
    float s = out[t];  // holds b_lin from init
    #pragma unroll 4
    for (int g2 = 0; g2 < NWG; ++g2) s += partials[(size_t)g2 * SEQ + t];
    out[t] = s;
}

__global__ __launch_bounds__(TPB)
void lstm_kernel(const float* __restrict__ sentence,
                 const float* __restrict__ W_ih,
                 const float* __restrict__ W_hh,
                 const float* __restrict__ b_ih,
                 const float* __restrict__ b_hh,
                 const float* __restrict__ W_lin,
                 unsigned* flags, float* h_buf,
                 float* partials, float* out, int use_partials)
{
    __shared__ float s_sent[SEQ];   // 32 KiB: whole input, read once from HBM
    __shared__ float s_part[WPW];
    const int tid = threadIdx.x;
    const int g = blockIdx.x;
    const int w = tid >> 6;   // wave id = local h-index
    const int l = tid & 63;   // lane
    const int j = g * WPW + w;

    for (int i = tid; i < SEQ; i += TPB) s_sent[i] = sentence[i];

    // Load this thread's W_hh slice into registers once.
    // Lane l owns columns {k*256 + l*4 + q : k=0..3, q=0..3} of each gate row
    // (perfectly coalesced float4 loads; matches the h-load pattern below).
    float Wreg[4][16];
    #pragma unroll
    for (int gate = 0; gate < 4; ++gate) {
        const float* rowp = W_hh + (size_t)(j + gate * HID) * HID;
        #pragma unroll
        for (int k = 0; k < 4; ++k) {
            float4 v = *reinterpret_cast<const float4*>(rowp + k * 256 + l * 4);
            Wreg[gate][k * 4 + 0] = v.x; Wreg[gate][k * 4 + 1] = v.y;
            Wreg[gate][k * 4 + 2] = v.z; Wreg[gate][k * 4 + 3] = v.w;
        }
    }
    float wih[4], bb[4];
    #pragma unroll
    for (int gate = 0; gate < 4; ++gate) {
        int row = j + gate * HID;
        wih[gate] = W_ih[row];
        bb[gate]  = b_ih[row] + b_hh[row];  // fold biases once
    }
    const float wlin = W_lin[j];
    float c = 0.0f;

    __syncthreads();  // sentence staged

    for (int t = 0; t < SEQ; ++t) {
        const float* hb  = h_buf + ((t)     & 1) * HID;  // h_{t-1}
        float*       hnb = h_buf + ((t + 1) & 1) * HID;  // h_t

        if (t > 0) {
            if (w == 0) {
                // One wave polls all 128 per-wg flags (coalesced 512B load).
                int guard = 0;
                for (;;) {
                    unsigned a  = __hip_atomic_load(&flags[l],      __ATOMIC_RELAXED, __HIP_MEMORY_SCOPE_AGENT);
                    unsigned b2 = __hip_atomic_load(&flags[64 + l], __ATOMIC_RELAXED, __HIP_MEMORY_SCOPE_AGENT);
                    if (__all(a >= (unsigned)t && b2 >= (unsigned)t)) break;
                    if (++guard > (1 << 18)) break;  // bailout: fail loud, don't hang
                }
                // Invalidate L1 + XCD-L2 so the plain h loads below are fresh.
                __builtin_amdgcn_fence(__ATOMIC_ACQUIRE, "agent");
            }
            __syncthreads();
        }

        // Each wave reads all of h_{t-1} (4 KiB, coalesced, L3-fresh post-inv).
        float h[16];
        #pragma unroll
        for (int k = 0; k < 4; ++k) {
            float4 v = *reinterpret_cast<const float4*>(hb + k * 256 + l * 4);
            h[k * 4 + 0] = v.x; h[k * 4 + 1] = v.y;
            h[k * 4 + 2] = v.z; h[k * 4 + 3] = v.w;
        }

        float acc0 = 0.f, acc1 = 0.f, acc2 = 0.f, acc3 = 0.f;
        #pragma unroll
        for (int m = 0; m < 16; ++m) {
            acc0 = fmaf(Wreg[0][m], h[m], acc0);
            acc1 = fmaf(Wreg[1][m], h[m], acc1);
            acc2 = fmaf(Wreg[2][m], h[m], acc2);
            acc3 = fmaf(Wreg[3][m], h[m], acc3);
        }
        // Butterfly allreduce across the 64-lane wave: all lanes get full sums.
        #pragma unroll
        for (int m = 1; m < 64; m <<= 1) {
            acc0 += __shfl_xor(acc0, m, 64);
            acc1 += __shfl_xor(acc1, m, 64);
            acc2 += __shfl_xor(acc2, m, 64);
            acc3 += __shfl_xor(acc3, m, 64);
        }

        float x  = s_sent[t];
        float zi = fmaf(wih[0], x, acc0 + bb[0]);
        float zf = fmaf(wih[1], x, acc1 + bb[1]);
        float zg = fmaf(wih[2], x, acc2 + bb[2]);
        float zo = fmaf(wih[3], x, acc3 + bb[3]);
        float ig = fast_sigmoid(zi);
        float fg = fast_sigmoid(zf);
        float gg = fast_tanh(zg);
        float og = fast_sigmoid(zo);
        c = fmaf(fg, c, ig * gg);            // identical on all lanes
        float hn = og * fast_tanh(c);

        if (l == 0) {
            // Publish h_t[j]: agent-scope store bypasses the (stale-able) XCD L2.
            __hip_atomic_store(&hnb[j], hn, __ATOMIC_RELAXED, __HIP_MEMORY_SCOPE_AGENT);
            s_part[w] = wlin * hn;
        }
        __syncthreads();  // drains each wave's vmcnt(0): all 8 h-stores complete
        if (tid == 0) {
            __hip_atomic_store(&flags[g], (unsigned)(t + 1), __ATOMIC_RELEASE, __HIP_MEMORY_SCOPE_AGENT);
            // Off the critical path: per-wg contribution to out[t].
            float p = s_part[0] + s_part[1] + s_part[2] + s_part[3] +
                      s_part[4] + s_part[5] + s_part[6] + s_part[7];
            if (use_partials) partials[(size_t)g * SEQ + t] = p;
            else atomicAdd(&out[t], p);
        }
    }
}

extern "C" void kernel_launch(void* const* d_in, const int* in_sizes, int n_in,
                              void* d_out, int out_size, void* d_ws, size_t ws_size,
                              hipStream_t stream) {
    const float* sentence = (const float*)d_in[0];
    const float* W_ih     = (const float*)d_in[1];
    const float* W_hh     = (const float*)d_in[2];
    const float* b_ih     = (const float*)d_in[3];
    const float* b_hh     = (const float*)d_in[4];
    const float* W_lin    = (const float*)d_in[5];
    const float* b_lin    = (const float*)d_in[6];
    float* out = (float*)d_out;

    char* ws = (char*)d_ws;
    unsigned* flags = (unsigned*)ws;               // 512 B
    float* h_buf    = (float*)(ws + 512);          // 8 KiB (double-buffered h)
    float* partials = (float*)(ws + 512 + 2 * HID * sizeof(float));
    const size_t need = 512 + 2 * HID * sizeof(float) + (size_t)NWG * SEQ * sizeof(float);
    int use_partials = (ws_size >= need) ? 1 : 0;  // fallback: atomicAdd into out

    hipLaunchKernelGGL(init_kernel, dim3(SEQ / 256), dim3(256), 0, stream,
                       flags, h_buf, out, b_lin);
    hipLaunchKernelGGL(lstm_kernel, dim3(NWG), dim3(TPB), 0, stream,
                       sentence, W_ih, W_hh, b_ih, b_hh, W_lin,
                       flags, h_buf, partials, out, use_partials);
    if (use_partials) {
        hipLaunchKernelGGL(finish_kernel, dim3(SEQ / 256), dim3(256), 0, stream,
                           partials, out);
    }
}

// Round 2
// 26203.699 us; speedup vs baseline: 1.9759x; 1.9759x over previous
//
#include <hip/hip_runtime.h>

// LSTM(H=1024) over SEQ=8192, input_size=1, fused persistent kernel, round 2.
// 128 wgs x 512 threads, 1 wg/CU. Wave w of wg g owns h-index j=8g+w and its 4
// gate rows of W_hh held in 64 VGPRs/thread (launch_bounds(512,2) => 256-VGPR
// budget; asm "+v" pins stop load re-materialization).
// Cross-wg recurrence: (h,step-tag) packed in 8B slots, double-buffered,
// agent-scope relaxed atomics (coherence-point access, NO cache-invalidating
// fence). One L3 round trip per step instead of publish->flag->poll->read.

#define SEQ 8192
#define HID 1024
#define NWG 128
#define TPB 512
#define WPW 8   // waves (h-indices) per workgroup

typedef unsigned long long ull;

__device__ __forceinline__ float fast_sigmoid(float z) {
    float e = __builtin_amdgcn_exp2f(-1.4426950408889634f * z);
    return 1.0f / (1.0f + e);
}
__device__ __forceinline__ float fast_tanh(float x) {
    float e = __builtin_amdgcn_exp2f(2.8853900817779268f * x);
    return 1.0f - 2.0f / (e + 1.0f);
}

// ws/out are re-poisoned 0xAA before every launch: zero the slot tags,
// prefill out[t] = b_lin (partials are fully overwritten each step).
__global__ void init_kernel(ull* slots, float* out, const float* __restrict__ b_lin) {
    int i = blockIdx.x * blockDim.x + threadIdx.x;
    if (i < 2 * HID) slots[i] = 0ull;   // h=0.0f, tag=0
    if (i < SEQ) out[i] = b_lin[0];
}

__global__ void finish_kernel(const float* __restrict__ partials,
                              float* __restrict__ out) {
    int t = blockIdx.x * blockDim.x + threadIdx.x;
    if (t >= SEQ) return;
    float s = out[t];  // holds b_lin from init
    #pragma unroll 4
    for (int g2 = 0; g2 < NWG; ++g2) s += partials[(size_t)g2 * SEQ + t];
    out[t] = s;
}

__global__ __launch_bounds__(TPB, 2)
void lstm_kernel(const float* __restrict__ sentence,
                 const float* __restrict__ W_ih,
                 const float* __restrict__ W_hh,
                 const float* __restrict__ b_ih,
                 const float* __restrict__ b_hh,
                 const float* __restrict__ W_lin,
                 ull* slots, float* partials, float* out, int use_partials)
{
    __shared__ float s_sent[SEQ];      // 32 KiB: whole input, read once
    __shared__ float s_h[HID];         // staged h_{t-1}
    __shared__ float s_part[2][WPW];   // per-wave W_lin partials, dbuf'd
    const int tid = threadIdx.x;
    const int g = blockIdx.x;
    const int w = tid >> 6;   // wave id = local h-index
    const int l = tid & 63;   // lane
    const int j = g * WPW + w;

    for (int i = tid; i < SEQ; i += TPB) s_sent[i] = sentence[i];

    // W_hh slice into registers once. Lane l owns columns {k*64 + l : k=0..15}
    // of each of this wave's 4 gate rows (coalesced 256B/wave dword loads;
    // matches the s_h[k*64+l] read pattern below).
    float Wreg[4][16];
    #pragma unroll
    for (int gate = 0; gate < 4; ++gate) {
        const float* rowp = W_hh + (size_t)(j + gate * HID) * HID;
        #pragma unroll
        for (int k = 0; k < 16; ++k) Wreg[gate][k] = rowp[k * 64 + l];
    }
    // Pin: make values opaque so LLVM cannot re-materialize the loads in-loop.
    #pragma unroll
    for (int gate = 0; gate < 4; ++gate)
        #pragma unroll
        for (int k = 0; k < 16; ++k)
            asm volatile("" : "+v"(Wreg[gate][k]));

    float wih[4], bb[4];
    #pragma unroll
    for (int gate = 0; gate < 4; ++gate) {
        int row = j + gate * HID;
        wih[gate] = W_ih[row];
        bb[gate]  = b_ih[row] + b_hh[row];
    }
    const float wlin = W_lin[j];
    float c = 0.0f;

    ull* const buf0 = slots;
    ull* const buf1 = slots + HID;

    __syncthreads();  // sentence staged

    for (int t = 0; t < SEQ; ++t) {
        // ---- acquire h_{t-1} into LDS ----
        if (t == 0) {
            s_h[tid] = 0.0f;
            s_h[tid + TPB] = 0.0f;
        } else {
            ull* b = (t & 1) ? buf1 : buf0;
            const unsigned tt = (unsigned)t;
            ull v0 = 0, v1 = 0;
            int guard = 0;
            for (;;) {
                v0 = __hip_atomic_load(&b[tid],       __ATOMIC_RELAXED, __HIP_MEMORY_SCOPE_AGENT);
                v1 = __hip_atomic_load(&b[tid + TPB], __ATOMIC_RELAXED, __HIP_MEMORY_SCOPE_AGENT);
                if ((unsigned)(v0 >> 32) == tt && (unsigned)(v1 >> 32) == tt) break;
                if (++guard > (1 << 22)) break;  // fail loud, don't hang
            }
            s_h[tid]       = __uint_as_float((unsigned)v0);
            s_h[tid + TPB] = __uint_as_float((unsigned)v1);
        }
        __syncthreads();

        // Drain previous step's output contribution (ordered by the barrier).
        if (t > 0 && tid == 0) {
            const float* sp = s_part[(t - 1) & 1];
            float p = sp[0] + sp[1] + sp[2] + sp[3] + sp[4] + sp[5] + sp[6] + sp[7];
            if (use_partials) partials[(size_t)g * SEQ + (t - 1)] = p;
            else atomicAdd(&out[t - 1], p);
        }

        // ---- z = W_hh[j,:] . h  (wave-wide) ----
        float h[16];
        #pragma unroll
        for (int k = 0; k < 16; ++k) h[k] = s_h[k * 64 + l];

        float acc0 = 0.f, acc1 = 0.f, acc2 = 0.f, acc3 = 0.f;
        #pragma unroll
        for (int m = 0; m < 16; ++m) {
            acc0 = fmaf(Wreg[0][m], h[m], acc0);
            acc1 = fmaf(Wreg[1][m], h[m], acc1);
            acc2 = fmaf(Wreg[2][m], h[m], acc2);
            acc3 = fmaf(Wreg[3][m], h[m], acc3);
        }
        #pragma unroll
        for (int m = 1; m < 64; m <<= 1) {
            acc0 += __shfl_xor(acc0, m, 64);
            acc1 += __shfl_xor(acc1, m, 64);
            acc2 += __shfl_xor(acc2, m, 64);
            acc3 += __shfl_xor(acc3, m, 64);
        }

        float x  = s_sent[t];
        float zi = fmaf(wih[0], x, acc0 + bb[0]);
        float zf = fmaf(wih[1], x, acc1 + bb[1]);
        float zg = fmaf(wih[2], x, acc2 + bb[2]);
        float zo = fmaf(wih[3], x, acc3 + bb[3]);
        float ig = fast_sigmoid(zi);
        float fg = fast_sigmoid(zf);
        float gg = fast_tanh(zg);
        float og = fast_sigmoid(zo);
        c = fmaf(fg, c, ig * gg);            // identical on all lanes
        float hn = og * fast_tanh(c);

        // ---- publish (h_t[j], tag=t+1); fire-and-forget, no fence ----
        if (l == 0) {
            ull pk = ((ull)(unsigned)(t + 1) << 32) | (ull)__float_as_uint(hn);
            ull* nb = ((t + 1) & 1) ? buf1 : buf0;
            __hip_atomic_store(&nb[j], pk, __ATOMIC_RELAXED, __HIP_MEMORY_SCOPE_AGENT);
            asm volatile("" ::: "memory");   // don't sink the store past the next poll
            s_part[t & 1][w] = wlin * hn;
        }
    }

    __syncthreads();
    if (tid == 0) {
        const float* sp = s_part[(SEQ - 1) & 1];
        float p = sp[0] + sp[1] + sp[2] + sp[3] + sp[4] + sp[5] + sp[6] + sp[7];
        if (use_partials) partials[(size_t)g * SEQ + (SEQ - 1)] = p;
        else atomicAdd(&out[SEQ - 1], p);
    }
}

extern "C" void kernel_launch(void* const* d_in, const int* in_sizes, int n_in,
                              void* d_out, int out_size, void* d_ws, size_t ws_size,
                              hipStream_t stream) {
    const float* sentence = (const float*)d_in[0];
    const float* W_ih     = (const float*)d_in[1];
    const float* W_hh     = (const float*)d_in[2];
    const float* b_ih     = (const float*)d_in[3];
    const float* b_hh     = (const float*)d_in[4];
    const float* W_lin    = (const float*)d_in[5];
    const float* b_lin    = (const float*)d_in[6];
    float* out = (float*)d_out;

    char* ws = (char*)d_ws;
    ull* slots      = (ull*)ws;                          // 16 KiB (2 x 1024 x 8B)
    float* partials = (float*)(ws + 2 * HID * sizeof(ull));
    const size_t need = 2 * HID * sizeof(ull) + (size_t)NWG * SEQ * sizeof(float);
    int use_partials = (ws_size >= need) ? 1 : 0;        // fallback: atomicAdd

    hipLaunchKernelGGL(init_kernel, dim3(SEQ / 256), dim3(256), 0, stream,
                       slots, out, b_lin);
    hipLaunchKernelGGL(lstm_kernel, dim3(NWG), dim3(TPB), 0, stream,
                       sentence, W_ih, W_hh, b_ih, b_hh, W_lin,
                       slots, partials, out, use_partials);
    if (use_partials) {
        hipLaunchKernelGGL(finish_kernel, dim3(SEQ / 256), dim3(256), 0, stream,
                           partials, out);
    }
}